// Round 11
// baseline (99.017 us; speedup 1.0000x reference)
//
#include <hip/hip_runtime.h>
#include <stdint.h>

// QuantLinear eval forward — v10: v9 + last VALU scraps.
// vs v9 (verified absmax 0, dur 97.35): (1) clamp via v_med3_f32 (1 op, was
// min+max); (2) quantize pack via v_cvt_pk_u8_f32 (1 op/elem, was cvt+shl+or)
// + single qw+qw doubling for the x2 premultiply (2q<=30, no byte carry);
// (3) scalarized zero/unit fast path (InMin==+0 && scale==1): skips the
// quantize sub (x-0 exact) and the epilogue FMA (a*1+0 exact).
// Core algebra unchanged: q bytes = 2q, mask bytes = 137, init 1918:
// udot4 -> 274*(y+7); >>12 = round(y/15) exact. TERM = 5 full-rate ops.
// Memory skeleton proven r2-r10: 4x1KB coalesced wave preloads, wave-private
// LDS transpose (no barriers anywhere), contiguous 1KB stores.

#if __has_builtin(__builtin_amdgcn_udot4)
#define HAVE_UDOT4 1
#else
#define HAVE_UDOT4 0
#endif

#if __has_builtin(__builtin_amdgcn_cvt_pk_u8_f32)
#define HAVE_CVTPK 1
#else
#define HAVE_CVTPK 0
#endif

typedef float f32x4 __attribute__((ext_vector_type(4)));

#if HAVE_UDOT4
// q2 bytes = 2q, mask bytes = 137, init 1918 -> 274*(y+7); >>12 = round(y/15)
#define TERM(q2, mp, mm)                                                    \
    ((int)(__builtin_amdgcn_udot4((q2), (mp), 1918u, false) >> 12) -        \
     (int)(__builtin_amdgcn_udot4((q2), (mm), 1918u, false) >> 12))
#define MBYTE 137u
#define BPB 3            // popc bits per set mask byte
#else
#define BSUM(x) ((int)((uint32_t)((x) * 0x01010101u) >> 24))
__device__ __forceinline__ int rnd15f(int x) {
    return (int)(__umul24((unsigned)x, 274u) >> 12);
}
#define TERM(q, mp, mm)                                                     \
    (rnd15f(BSUM((q) & (mp)) + 7) - rnd15f(BSUM((q) & (mm)) + 7))
#define MBYTE 0xFFu
#define BPB 8
#endif

// quantize one element (already min-shifted/scaled) -> integral float in [0,15]
__device__ __forceinline__ float qstep(float e) {
    float rr = rintf(__fmul_rn(e, 15.0f));
    return __builtin_amdgcn_fmed3f(rr, 0.0f, 15.0f);   // median == clamp here
}

// pack 4 integral floats [0,15] into bytes; double if premultiplied path
__device__ __forceinline__ uint32_t qpack(float r0, float r1, float r2, float r3) {
#if HAVE_CVTPK
    uint32_t pk = 0;
    pk = __builtin_amdgcn_cvt_pk_u8_f32(r0, 0, pk);
    pk = __builtin_amdgcn_cvt_pk_u8_f32(r1, 1, pk);
    pk = __builtin_amdgcn_cvt_pk_u8_f32(r2, 2, pk);
    pk = __builtin_amdgcn_cvt_pk_u8_f32(r3, 3, pk);
#else
    uint32_t pk = ((uint32_t)(int)r0)
                | (((uint32_t)(int)r1) << 8)
                | (((uint32_t)(int)r2) << 16)
                | (((uint32_t)(int)r3) << 24);
#endif
#if HAVE_UDOT4
    return pk + pk;          // bytes 2q, no cross-byte carry (2*15=30)
#else
    return pk;
#endif
}

// MODE: 0 = InMin==+0 && scale==1 ; 1 = scale==1 ; 2 = general
template <int MODE>
__device__ __forceinline__ void run_slabs(
    const float4* f, float* __restrict__ out, size_t R0, int lane, int ogrp,
    int rsel, uint32_t* xp,
    const uint4& P0, const uint4& P1, const uint4& P2, const uint4& P3,
    const uint4& M0, const uint4& M1, const uint4& M2, const uint4& M3,
    const float4& bias, float InMin, float scale)
{
#define QE(E)                                                               \
    (MODE == 0 ? qstep(E)                                                   \
     : MODE == 1 ? qstep(__fsub_rn((E), InMin))                             \
                 : qstep(__fdiv_rn(__fsub_rn((E), InMin), scale)))

#define EPI(A, B)                                                           \
    (MODE == 0 ? (float)(A)                                                 \
               : __fadd_rn(__fmul_rn((float)(A), scale), (B)))

#define ROWCOMP(q0, q1, q2, q3, dst)                                        \
        {                                                                   \
            int a0 = TERM(q0, P0.x, M0.x) + TERM(q1, P0.y, M0.y)            \
                   + TERM(q2, P0.z, M0.z) + TERM(q3, P0.w, M0.w);           \
            int a1 = TERM(q0, P1.x, M1.x) + TERM(q1, P1.y, M1.y)            \
                   + TERM(q2, P1.z, M1.z) + TERM(q3, P1.w, M1.w);           \
            int a2 = TERM(q0, P2.x, M2.x) + TERM(q1, P2.y, M2.y)            \
                   + TERM(q2, P2.z, M2.z) + TERM(q3, P2.w, M2.w);           \
            int a3 = TERM(q0, P3.x, M3.x) + TERM(q1, P3.y, M3.y)            \
                   + TERM(q2, P3.z, M3.z) + TERM(q3, P3.w, M3.w);           \
            f32x4 res;                                                      \
            res.x = EPI(a0, bias.x);                                        \
            res.y = EPI(a1, bias.y);                                        \
            res.z = EPI(a2, bias.z);                                        \
            res.w = EPI(a3, bias.w);                                        \
            *(f32x4*)(dst) = res;                                           \
        }

#pragma unroll
    for (int K = 0; K < 4; ++K) {
        const float4 F = f[K];
        const uint32_t qw = qpack(QE(F.x), QE(F.y), QE(F.z), QE(F.w));
        xp[lane] = qw;
        const uint4 qA = *(const uint4*)(xp + (rsel << 2));
        const uint4 qB = *(const uint4*)(xp + 32 + (rsel << 2));
        float* p0 = out + (R0 + (size_t)K * 16 + rsel) * 32 + (ogrp << 2);
        ROWCOMP(qA.x, qA.y, qA.z, qA.w, p0);
        ROWCOMP(qB.x, qB.y, qB.z, qB.w, p0 + 256);
    }
#undef ROWCOMP
#undef EPI
#undef QE
}

__global__ __launch_bounds__(256) void qlin_main(
    const float* __restrict__ in, const float* __restrict__ wgt,
    const float* __restrict__ pmin, const float* __restrict__ pmax,
    float* __restrict__ out, int nrows)
{
    // per-wave private LDS: 128 P + 128 M mask words, 32 bias, 64 xpose
    __shared__ __align__(16) uint32_t sP[4][128];
    __shared__ __align__(16) uint32_t sM[4][128];
    __shared__ __align__(16) float    sB[4][32];
    __shared__ __align__(16) uint32_t sX[4][64];

    const int t = threadIdx.x;
    const int lane = t & 63;
    const int wv = t >> 6;
    const size_t R0 = ((size_t)blockIdx.x * 4 + wv) * 64;   // 64 rows per wave
    (void)nrows;   // grid covers rows exactly

    // issue all 4 slab loads NOW; per-wave prologue hides the latency
    const float4* inp = (const float4*)in + R0 * 4 + lane;
    float4 f[4];
    f[0] = inp[0]; f[1] = inp[64]; f[2] = inp[128]; f[3] = inp[192];

    // --- per-wave mask build (no barrier: wave-internal DS ordering) ---
#pragma unroll
    for (int k = 0; k < 2; ++k) {
        const int w = lane * 2 + k;            // w = o*4+c
        const float4 wf = *(const float4*)(wgt + w * 4);
        uint32_t mp = 0, mm = 0;
        const float e[4] = { wf.x, wf.y, wf.z, wf.w };
#pragma unroll
        for (int j = 0; j < 4; ++j) {
            if (e[j] > 0.0f) mp |= MBYTE << (8 * j);
            if (e[j] < 0.0f) mm |= MBYTE << (8 * j);
        }
        sP[wv][w] = mp;
        sM[wv][w] = mm;
    }
    // --- per-wave bias: lane o<32 from mask popcounts (exact) ---
    if (lane < 32) {
        int pc = 0;
#pragma unroll
        for (int c = 0; c < 4; ++c)
            pc += __popc(sP[wv][lane * 4 + c]) - __popc(sM[wv][lane * 4 + c]);
        sB[wv][lane] = __fmul_rn(pmin[0], (float)(pc / BPB));
    }

    const int ogrp = lane & 7;        // 4-output group this lane owns
    const int rsel = lane >> 3;       // row-within-8 this lane owns
    uint32_t* xp = sX[wv];

    // hoist this lane's 4x4 P/M mask words into registers
    const uint4 P0 = *(const uint4*)&sP[wv][(ogrp * 4 + 0) * 4];
    const uint4 P1 = *(const uint4*)&sP[wv][(ogrp * 4 + 1) * 4];
    const uint4 P2 = *(const uint4*)&sP[wv][(ogrp * 4 + 2) * 4];
    const uint4 P3 = *(const uint4*)&sP[wv][(ogrp * 4 + 3) * 4];
    const uint4 M0 = *(const uint4*)&sM[wv][(ogrp * 4 + 0) * 4];
    const uint4 M1 = *(const uint4*)&sM[wv][(ogrp * 4 + 1) * 4];
    const uint4 M2 = *(const uint4*)&sM[wv][(ogrp * 4 + 2) * 4];
    const uint4 M3 = *(const uint4*)&sM[wv][(ogrp * 4 + 3) * 4];
    const float4 bias = *(const float4*)&sB[wv][ogrp * 4];

    const float InMin = pmin[0];
    const float scale = __fsub_rn(pmax[0], InMin);
    // scalarized mode select: s_cmp + s_cbranch, only the taken path runs
    const uint32_t sbits = __builtin_amdgcn_readfirstlane(__float_as_uint(scale));
    const uint32_t mbits = __builtin_amdgcn_readfirstlane(__float_as_uint(InMin));
    const bool unit = (sbits == 0x3f800000u);
    const bool zu   = unit && (mbits == 0u);   // InMin==+0 && scale==1

    if (zu)
        run_slabs<0>(f, out, R0, lane, ogrp, rsel, xp,
                     P0, P1, P2, P3, M0, M1, M2, M3, bias, InMin, scale);
    else if (unit)
        run_slabs<1>(f, out, R0, lane, ogrp, rsel, xp,
                     P0, P1, P2, P3, M0, M1, M2, M3, bias, InMin, scale);
    else
        run_slabs<2>(f, out, R0, lane, ogrp, rsel, xp,
                     P0, P1, P2, P3, M0, M1, M2, M3, bias, InMin, scale);
}

extern "C" void kernel_launch(void* const* d_in, const int* in_sizes, int n_in,
                              void* d_out, int out_size, void* d_ws, size_t ws_size,
                              hipStream_t stream) {
    (void)n_in; (void)d_ws; (void)ws_size; (void)out_size;
    const float* in  = (const float*)d_in[0];
    const float* wgt = (const float*)d_in[1];
    const float* mn  = (const float*)d_in[2];
    const float* mx  = (const float*)d_in[3];
    float* out = (float*)d_out;
    const int nrows = in_sizes[0] / 16;        // 524288
    const int blocks = nrows / 256;            // 2048 blocks x 4 waves x 64 rows
    qlin_main<<<blocks, 256, 0, stream>>>(in, wgt, mn, mx, out, nrows);
}